// Round 12
// baseline (830.043 us; speedup 1.0000x reference)
//
#include <hip/hip_runtime.h>
#include <hip/hip_bf16.h>

#define LNUM 128
#define NNODES 30000
#define NEDGES 150000
#define NSTEPS 5

// NOTE (r17 discovery): d_out is FLOAT32 (reference is pure jnp.float32).
// r11 post-mortem: traffic cut 196->142MB, time NULL -> not traffic-bound;
// atomics not pacer (halved, null). Shared pacer = per-chunk cadence:
// 2 barriers/chunk expose stage L2 latency (~300cy) + 1-deep gather prefetch
// exposes L2-miss (~600cy). r12 (scheduling only, bit-identical math):
//  - dbuf weight LDS (2x8KB, r6-verified rotation), ONE barrier per chunk;
//    stage k+1 issued right after barrier, drained a full phase later.
//  - 2-deep data prefetch (qnA/qnB), gather latency covered ~2 phases.
//  - W2 ch0 staged during last L1 iter (no drain at layer boundary).
// LDS 32KB -> 5 blocks/CU.

typedef _Float16 f16;
typedef __attribute__((ext_vector_type(2))) _Float16 f16x2;
typedef __attribute__((ext_vector_type(8))) _Float16 f16x8;
typedef __attribute__((ext_vector_type(4))) float f32x4;

__device__ __forceinline__ void glds16(const void* g, void* l) {
    __builtin_amdgcn_global_load_lds(
        (const __attribute__((address_space(1))) void*)g,
        (__attribute__((address_space(3))) void*)l, 16, 0, 0);
}

__device__ __forceinline__ void atomic_pk_add(f16* addr, f16 lo, f16 hi) {
#if __has_builtin(__builtin_amdgcn_global_atomic_fadd_v2f16)
    f16x2 v; v[0] = lo; v[1] = hi;
    __builtin_amdgcn_global_atomic_fadd_v2f16(
        (__attribute__((address_space(1))) f16x2*)addr, v);
#else
    uint32_t* p = (uint32_t*)addr;
    uint32_t old = *p, assumed;
    do {
        assumed = old;
        union { uint32_t u; f16 h[2]; } c; c.u = assumed;
        c.h[0] += lo; c.h[1] += hi;
        old = atomicCAS(p, assumed, c.u);
    } while (old != assumed);
#endif
}

// ---------------------------------------------------------------------------
// Legacy VALU MLP core: still used by the (small) encode_nodes kernel.
// ---------------------------------------------------------------------------
template<int ROWS, int K, int KP>
__device__ __forceinline__ void mlp_apply(
    const float* __restrict__ xs, float* __restrict__ hv,
    float* __restrict__ mu_s, float* __restrict__ rs_s,
    const float* __restrict__ W1, const float* __restrict__ b1,
    const float* __restrict__ W2, const float* __restrict__ b2,
    const float* __restrict__ g,  const float* __restrict__ be,
    float out[ROWS])
{
    const int t = threadIdx.x;
    float acc[ROWS];
    {
        const float bb = b1[t];
        #pragma unroll
        for (int r = 0; r < ROWS; r++) acc[r] = bb;
    }
    int k = 0;
    for (; k + 4 <= K; k += 4) {
        const float w0 = W1[(k + 0) * LNUM + t];
        const float w1 = W1[(k + 1) * LNUM + t];
        const float w2 = W1[(k + 2) * LNUM + t];
        const float w3 = W1[(k + 3) * LNUM + t];
        #pragma unroll
        for (int r = 0; r < ROWS; r++) {
            const float4 x = *(const float4*)(xs + r * KP + k);
            acc[r] = fmaf(x.x, w0, acc[r]);
            acc[r] = fmaf(x.y, w1, acc[r]);
            acc[r] = fmaf(x.z, w2, acc[r]);
            acc[r] = fmaf(x.w, w3, acc[r]);
        }
    }
    for (; k < K; ++k) {
        const float w = W1[k * LNUM + t];
        #pragma unroll
        for (int r = 0; r < ROWS; r++) acc[r] = fmaf(xs[r * KP + k], w, acc[r]);
    }
    #pragma unroll
    for (int r = 0; r < ROWS; r++) hv[r * LNUM + t] = fmaxf(acc[r], 0.f);
    __syncthreads();
    {
        const float bb = b2[t];
        #pragma unroll
        for (int r = 0; r < ROWS; r++) acc[r] = bb;
    }
    for (int k2 = 0; k2 < LNUM; k2 += 4) {
        const float w0 = W2[(k2 + 0) * LNUM + t];
        const float w1 = W2[(k2 + 1) * LNUM + t];
        const float w2 = W2[(k2 + 2) * LNUM + t];
        const float w3 = W2[(k2 + 3) * LNUM + t];
        #pragma unroll
        for (int r = 0; r < ROWS; r++) {
            const float4 x = *(const float4*)(hv + r * LNUM + k2);
            acc[r] = fmaf(x.x, w0, acc[r]);
            acc[r] = fmaf(x.y, w1, acc[r]);
            acc[r] = fmaf(x.z, w2, acc[r]);
            acc[r] = fmaf(x.w, w3, acc[r]);
        }
    }
    __syncthreads();
    #pragma unroll
    for (int r = 0; r < ROWS; r++) hv[r * LNUM + t] = fmaxf(acc[r], 0.f);
    __syncthreads();
    if (t < ROWS) {
        float s = 0.f, s2 = 0.f;
        for (int kk = 0; kk < LNUM; kk++) {
            const float v = hv[t * LNUM + kk];
            s += v; s2 += v * v;
        }
        const float m = s * (1.0f / LNUM);
        mu_s[t] = m;
        rs_s[t] = rsqrtf(fmaxf(s2 * (1.0f / LNUM) - m * m, 0.f) + 1e-5f);
    }
    __syncthreads();
    const float gg = g[t], bbe = be[t];
    #pragma unroll
    for (int r = 0; r < ROWS; r++)
        out[r] = fmaf(gg * (hv[r * LNUM + t] - mu_s[r]), rs_s[r], bbe);
}

__global__ __launch_bounds__(128) void encode_nodes_k(
    const float* __restrict__ u, const float* __restrict__ load_,
    const float* __restrict__ ntype,
    const float* __restrict__ W1, const float* __restrict__ b1,
    const float* __restrict__ W2, const float* __restrict__ b2,
    const float* __restrict__ g,  const float* __restrict__ be,
    f16* __restrict__ nl)
{
    constexpr int ROWS = 4, K = 12, KP = 12;
    __shared__ __align__(16) float xs[ROWS * KP];
    __shared__ __align__(16) float hv[ROWS * LNUM];
    __shared__ float mu_s[ROWS], rs_s[ROWS];
    const int t = threadIdx.x;
    const int base = blockIdx.x * ROWS;
    if (t < ROWS * K) {
        const int r = t / K, k = t % K;
        const int n = base + r;
        float v;
        if (k < 2)      v = u[n * 2 + k];
        else if (k < 3) v = load_[n];
        else            v = ntype[n * 9 + (k - 3)];
        xs[r * KP + k] = v;
    }
    __syncthreads();
    float out[ROWS];
    mlp_apply<ROWS, K, KP>(xs, hv, mu_s, rs_s, W1, b1, W2, b2, g, be, out);
    #pragma unroll
    for (int r = 0; r < ROWS; r++) nl[(base + r) * LNUM + t] = (f16)out[r];
}

// ---------------------------------------------------------------------------
// Weight prep: f32 [S][K][128] -> f16 hi tables transposed to [S][128][K].
// ---------------------------------------------------------------------------
#define PE1 245760   // 5*384*128 (edge W1)
#define PE2 81920    // 5*128*128 (edge W2)
#define PN1 163840   // 5*256*128 (node W1)
#define PN2 81920    // 5*128*128 (node W2)
#define PQ1 4096     // 128*32    (enc-edge W1, k-padded)
#define PQ2 16384    // 128*128   (enc-edge W2)
#define PTOT (PE1+PE2+PN1+PN2+PQ1+PQ2)

__global__ __launch_bounds__(256) void prep_w_all_k(
    const float* __restrict__ eW1, const float* __restrict__ eW2,
    const float* __restrict__ nW1, const float* __restrict__ nW2,
    const float* __restrict__ qW1, const float* __restrict__ qW2,
    f16* __restrict__ out)
{
    int j = blockIdx.x * 256 + threadIdx.x;
    if (j >= PTOT) return;
    const float* W; int K, kreal; f16* hi; f16* p = out;
    if (j < PE1) { W = eW1; K = 384; kreal = 384; hi = p; }
    else { p += PE1; j -= PE1;
    if (j < PE2) { W = eW2; K = 128; kreal = 128; hi = p; }
    else { p += PE2; j -= PE2;
    if (j < PN1) { W = nW1; K = 256; kreal = 256; hi = p; }
    else { p += PN1; j -= PN1;
    if (j < PN2) { W = nW2; K = 128; kreal = 128; hi = p; }
    else { p += PN2; j -= PN2;
    if (j < PQ1) { W = qW1; K = 32;  kreal = 5;   hi = p; }
    else { p += PQ1; j -= PQ1;
         { W = qW2; K = 128; kreal = 128; hi = p; } } } } } }
    const int k = j % K;
    const int rem = j / K;
    const int n = rem & 127;
    const int s = rem >> 7;
    const float v = (k < kreal) ? W[((size_t)s * kreal + k) * 128 + n] : 0.f;
    hi[j] = (f16)v;
}

// ---------------------------------------------------------------------------
// MFMA MLP, f16 weights/latents/aggr; PIPELINED staging (r12).
// 256 thr = 4 waves, 64 rows/block. Weight chunks (8KB) in a 2-buffer LDS
// rotation: ONE barrier per chunk; stage k+1 issued right after the barrier,
// drained at the NEXT barrier (full compute phase of hiding). Data gathers
// 2-deep in regs (qnA/qnB). Layer1->2 via f16 Y (16KB, XOR-swizzled).
// D layout (verified): edge = w*16+lg*4+reg, feature = mf*16+lr.
// MODE: 0 = edge block (Lat=nl16, io=el16 RMW, aggr16 pk-atomics)
//       1 = node block (Lat=aggr16, io=nl16 RMW)
//       2 = edge encoder (Fa=mesh_pos, Fb=u, io=el16 store)
// ---------------------------------------------------------------------------
template<int MODE, int NCH1, int K1S>
__global__ __launch_bounds__(256, 5) void mfma_mlp_k(
    const f16* __restrict__ Lat, const float* __restrict__ Fa,
    const float* __restrict__ Fb,
    f16* __restrict__ io, f16* __restrict__ aggr,
    const int* __restrict__ senders, const int* __restrict__ receivers,
    const f16* __restrict__ W1h, const float* __restrict__ b1,
    const f16* __restrict__ W2h, const float* __restrict__ b2,
    const float* __restrict__ gam, const float* __restrict__ bet,
    int nrows)
{
    __shared__ __align__(16) f16 WH[2][4096];              // dbuf [128][32] swz, 16KB
    __shared__ __align__(16) unsigned short Yh[64 * 128];  // f16, swizzled, 16KB

    const int t  = threadIdx.x;
    const int w  = t >> 6;
    const int l  = t & 63;
    const int lr = l & 15;
    const int lg = l >> 4;
    const int swz = lg ^ ((lr >> 1) & 3);
    const int base = blockIdx.x * 64;

    const int eg  = base + w * 16 + lr;    // this lane's gather row (A-row)
    const int egc = min(eg, nrows - 1);

    int sv = 0, rv = 0;
    if constexpr (MODE != 1) { sv = senders[egc]; rv = receivers[egc]; }

    float feat[8];
    if constexpr (MODE == 2) {
        const float ax = Fa[sv * 2], ay = Fa[sv * 2 + 1];
        const float bx = Fa[rv * 2], by = Fa[rv * 2 + 1];
        const float rx = ax - bx, ry = ay - by;
        feat[0] = rx; feat[1] = ry; feat[2] = sqrtf(rx * rx + ry * ry);
        feat[3] = Fb[sv * 2] - Fb[rv * 2];
        feat[4] = Fb[sv * 2 + 1] - Fb[rv * 2 + 1];
        feat[5] = 0.f; feat[6] = 0.f; feat[7] = 0.f;
    }

    // r5-verified cooperative stage of one 32-wide K chunk, into buffer buf.
    auto stage = [&](const f16* __restrict__ Wh, const int kst, const int kc,
                     const int buf) {
        #pragma unroll
        for (int i = 0; i < 2; i++) {
            const int c = 2 * w + i;
            const int ophys = c * 1024 + l * 16;
            const int olog  = ophys ^ (((ophys >> 7) & 3) << 4);
            const int row   = olog >> 6;
            const int slot  = (olog >> 4) & 3;
            glds16(Wh + (size_t)row * kst + kc * 32 + slot * 8,
                   (char*)&WH[buf][0] + c * 1024);
        }
    };

    // 2-deep data prefetch (f16 chunks only; MODE2 uses feat directly).
    uint4 qnA, qnB;
    auto prefetchTo = [&](int kc, uint4& q) {
        if constexpr (MODE == 0) {
            const f16* src;
            if (kc < 4)      src = Lat + (size_t)sv  * 128 + kc * 32 + lg * 8;
            else if (kc < 8) src = Lat + (size_t)rv  * 128 + (kc - 4) * 32 + lg * 8;
            else             src = io  + (size_t)egc * 128 + (kc - 8) * 32 + lg * 8;
            q = *(const uint4*)src;
        } else if constexpr (MODE == 1) {
            const f16* src;
            if (kc < 4) src = io  + (size_t)egc * 128 + kc * 32 + lg * 8;
            else        src = Lat + (size_t)egc * 128 + (kc - 4) * 32 + lg * 8;
            q = *(const uint4*)src;
        }
    };

    const f32x4 zero4 = {0.f, 0.f, 0.f, 0.f};
    f32x4 acc[8];
    #pragma unroll
    for (int mf = 0; mf < 8; mf++) acc[mf] = zero4;

    prefetchTo(0, qnA);
    if constexpr (NCH1 > 1) prefetchTo(1, qnB);
    stage(W1h, K1S, 0, 0);
    int cur = 0;

    // ---------------- layer 1 (ONE barrier per chunk, dbuf) --------------
    #pragma unroll
    for (int kc = 0; kc < NCH1; ++kc) {
        __syncthreads();   // drains stage(cur) [issued last iter] + gathers
        if (kc + 1 < NCH1) stage(W1h, K1S, kc + 1, cur ^ 1);
        else               stage(W2h, 128,  0,      cur ^ 1);   // L2 ch0
        f16x8 XHv, XLv;
        bool useXL = false;
        if constexpr (MODE == 2) {
            union { f16 h[8]; f16x8 v; } uh, ul;
            #pragma unroll
            for (int j = 0; j < 8; j++) {
                const float x = (lg == 0) ? feat[j] : 0.f;
                const f16 h = (f16)x;
                uh.h[j] = h;
                ul.h[j] = (f16)(x - (float)h);   // unscaled lo: exact sum
            }
            XHv = uh.v; XLv = ul.v; useXL = true;
        } else {
            union { uint4 q; f16x8 v; } cc;
            cc.q = (kc & 1) ? qnB : qnA;
            XHv = cc.v;
        }
        if (kc + 2 < NCH1) {             // refill the reg just consumed
            if (kc & 1) prefetchTo(kc + 2, qnB);
            else        prefetchTo(kc + 2, qnA);
        }
        #pragma unroll
        for (int mf = 0; mf < 8; mf++) {
            const int off = (mf * 16 + lr) * 64 + (swz << 4);
            const f16x8 wh = *(const f16x8*)((const char*)&WH[cur][0] + off);
            acc[mf] = __builtin_amdgcn_mfma_f32_16x16x32_f16(XHv, wh, acc[mf], 0, 0, 0);
            if (useXL)
                acc[mf] = __builtin_amdgcn_mfma_f32_16x16x32_f16(XLv, wh, acc[mf], 0, 0, 0);
        }
        cur ^= 1;
    }

    // layer-1 epilogue: bias+relu -> f16 Y at XOR-swizzled addr (r9-verified;
    // wave-private rows, no barrier needed).
    #pragma unroll
    for (int mf = 0; mf < 8; mf++) {
        const float bb1 = b1[mf * 16 + lr];
        #pragma unroll
        for (int reg = 0; reg < 4; reg++) {
            float v = acc[mf][reg] + bb1;
            v = fmaxf(v, 0.f);
            union { f16 h; unsigned short u; } cc; cc.h = (f16)v;
            const int row = w * 16 + lg * 4 + reg;
            const int cb  = (mf * 16 + lr) * 2;
            *(unsigned short*)((char*)Yh + row * 256 +
                               (cb ^ (((lg * 4 + reg) & 7) << 4))) = cc.u;
        }
        acc[mf] = zero4;
    }

    // ---------------- layer 2 (dbuf continues; 1 MFMA per mf) ------------
    #pragma unroll
    for (int kc = 0; kc < 4; ++kc) {
        __syncthreads();   // drains stage(cur) issued last iteration
        if (kc + 1 < 4) stage(W2h, 128, kc + 1, cur ^ 1);
        union { uint4 q; f16x8 v; } YH;
        {
            const int row = w * 16 + lr;
            const int cb  = (kc * 32 + lg * 8) * 2;
            YH.q = *(const uint4*)((const char*)Yh + row * 256 +
                                   (cb ^ ((lr & 7) << 4)));
        }
        #pragma unroll
        for (int mf = 0; mf < 8; mf++) {
            const int off = (mf * 16 + lr) * 64 + (swz << 4);
            const f16x8 wh = *(const f16x8*)((const char*)&WH[cur][0] + off);
            acc[mf] = __builtin_amdgcn_mfma_f32_16x16x32_f16(YH.v, wh, acc[mf], 0, 0, 0);
        }
        cur ^= 1;
    }

    // layer-2 epilogue (r5-verified): bias+relu+LN+apply+store (f16 io).
    float vv[8][4];
    float s1[4] = {0, 0, 0, 0}, s2[4] = {0, 0, 0, 0};
    #pragma unroll
    for (int mf = 0; mf < 8; mf++) {
        const float bb2 = b2[mf * 16 + lr];
        #pragma unroll
        for (int reg = 0; reg < 4; reg++) {
            float v = acc[mf][reg] + bb2;
            v = fmaxf(v, 0.f);
            vv[mf][reg] = v;
            s1[reg] += v; s2[reg] += v * v;
        }
    }
    #pragma unroll
    for (int m = 1; m < 16; m <<= 1) {
        #pragma unroll
        for (int reg = 0; reg < 4; reg++) {
            s1[reg] += __shfl_xor(s1[reg], m);
            s2[reg] += __shfl_xor(s2[reg], m);
        }
    }
    float gg[8], b8[8];
    #pragma unroll
    for (int mf = 0; mf < 8; mf++) {
        gg[mf] = gam[mf * 16 + lr];
        b8[mf] = bet[mf * 16 + lr];
    }

    #pragma unroll
    for (int reg = 0; reg < 4; reg++) {
        const float mu = s1[reg] * (1.f / 128.f);
        const float rs = rsqrtf(fmaxf(s2[reg] * (1.f / 128.f) - mu * mu, 0.f) + 1e-5f);
        const int row = w * 16 + lg * 4 + reg;
        const int idx = base + row;
        if (idx < nrows) {
            if constexpr (MODE == 0) {
                const int rc = receivers[idx];   // uniform across lr-group
                #pragma unroll
                for (int mf = 0; mf < 8; mf++) {
                    const int col = mf * 16 + lr;
                    const float o = gg[mf] * (vv[mf][reg] - mu) * rs + b8[mf];
                    // packed f16 atomic: even lane covers cols (c, c+1)
                    const float op = __shfl_xor(o, 1);
                    if ((lr & 1) == 0)
                        atomic_pk_add(aggr + (size_t)rc * 128 + col,
                                      (f16)o, (f16)op);            // segsum
                    f16* p = io + (size_t)idx * 128 + col;         // el res
                    *p = (f16)((float)*p + o);
                }
            } else if constexpr (MODE == 1) {
                #pragma unroll
                for (int mf = 0; mf < 8; mf++) {
                    const int col = mf * 16 + lr;
                    const float o = gg[mf] * (vv[mf][reg] - mu) * rs + b8[mf];
                    f16* p = io + (size_t)idx * 128 + col;         // nl res
                    *p = (f16)((float)*p + o);
                }
            } else {
                #pragma unroll
                for (int mf = 0; mf < 8; mf++) {
                    const int col = mf * 16 + lr;
                    const float o = gg[mf] * (vv[mf][reg] - mu) * rs + b8[mf];
                    io[(size_t)idx * 128 + col] = (f16)o;          // el enc
                }
            }
        }
    }
}

// Decoder -> FLOAT32 output, layout [TW, N, TD]. Reads f16 nl.
__global__ __launch_bounds__(128) void decode_k(
    const f16* __restrict__ nl,
    const float* __restrict__ W1, const float* __restrict__ b1,
    const float* __restrict__ W2, const float* __restrict__ b2,
    float* __restrict__ out)
{
    constexpr int NPB = 16;
    __shared__ __align__(16) float xs[NPB * LNUM];
    __shared__ float hh[NPB * 8];
    const int t = threadIdx.x;
    const int base = blockIdx.x * NPB;
    for (int r = 0; r < NPB; r++) xs[r * LNUM + t] = (float)nl[(base + r) * LNUM + t];
    __syncthreads();
    {
        const int node = t >> 3, j = t & 7;
        float a = b1[j];
        for (int k = 0; k < LNUM; k++) a = fmaf(xs[node * LNUM + k], W1[k * 8 + j], a);
        hh[node * 8 + j] = a / (1.f + expf(-a));
    }
    __syncthreads();
    for (int idx = t; idx < NPB * 10; idx += 128) {
        const int node = idx / 10, c = idx % 10;
        float a = b2[c];
        #pragma unroll
        for (int j = 0; j < 8; j++) a = fmaf(hh[node * 8 + j], W2[j * 10 + c], a);
        const int tt = c >> 1, d = c & 1;
        out[(size_t)tt * (NNODES * 2) + (size_t)(base + node) * 2 + d] =
            a * (float)(tt + 1);
    }
}

__global__ __launch_bounds__(256) void zero_k(float* __restrict__ p, int n)
{
    const int i = blockIdx.x * 256 + threadIdx.x;
    if (i < n) p[i] = 0.f;
}

// ---------------------------------------------------------------------------
extern "C" void kernel_launch(void* const* d_in, const int* in_sizes, int n_in,
                              void* d_out, int out_size, void* d_ws, size_t ws_size,
                              hipStream_t stream) {
    const float* F[34];
    for (int i = 0; i < 34; i++) F[i] = (const float*)d_in[i];
    const int* senders   = (const int*)d_in[4];
    const int* receivers = (const int*)d_in[5];

    const size_t nN = (size_t)NNODES * LNUM;
    const size_t nE = (size_t)NEDGES * LNUM;
    f16* nl16   = (f16*)d_ws;               // 7.68 MB
    f16* el16   = nl16 + nN;                // 38.4 MB
    f16* aggr16 = el16 + nE;                // 7.68 MB
    f16* wb     = aggr16 + nN;
    f16 *eW1h = wb;
    f16 *eW2h = eW1h + PE1;
    f16 *nW1h = eW2h + PE2;
    f16 *nW2h = nW1h + PN1;
    f16 *qW1h = nW2h + PN2;
    f16 *qW2h = qW1h + PQ1;

    prep_w_all_k<<<(PTOT + 255) / 256, 256, 0, stream>>>(
        F[18], F[20], F[24], F[26], F[12], F[14], wb);

    encode_nodes_k<<<NNODES / 4, 128, 0, stream>>>(
        F[2], F[3], F[1], F[6], F[7], F[8], F[9], F[10], F[11], nl16);

    const int egrid = (NEDGES + 63) / 64;   // 2344 blocks of 256 threads
    const int ngrid = (NNODES + 63) / 64;   // 469

    // edge encoder (MFMA, computed f32 features -> f16 el)
    mfma_mlp_k<2, 1, 32><<<egrid, 256, 0, stream>>>(
        nullptr, F[0], F[2], el16, nullptr, senders, receivers,
        qW1h, F[13], qW2h, F[15], F[16], F[17], NEDGES);

    for (int s = 0; s < NSTEPS; s++) {
        // zero f16 aggr (7.68MB) via f32-typed stores
        zero_k<<<(NNODES * 64 + 255) / 256, 256, 0, stream>>>(
            (float*)aggr16, NNODES * 64);
        mfma_mlp_k<0, 12, 384><<<egrid, 256, 0, stream>>>(
            nl16, nullptr, nullptr, el16, aggr16, senders, receivers,
            eW1h + (size_t)s * 384 * 128, F[19] + s * LNUM,
            eW2h + (size_t)s * 128 * 128, F[21] + s * LNUM,
            F[22] + s * LNUM, F[23] + s * LNUM, NEDGES);
        mfma_mlp_k<1, 8, 256><<<ngrid, 256, 0, stream>>>(
            aggr16, nullptr, nullptr, nl16, nullptr, nullptr, nullptr,
            nW1h + (size_t)s * 256 * 128, F[25] + s * LNUM,
            nW2h + (size_t)s * 128 * 128, F[27] + s * LNUM,
            F[28] + s * LNUM, F[29] + s * LNUM, NNODES);
    }

    decode_k<<<NNODES / 16, 128, 0, stream>>>(
        nl16, F[30], F[31], F[32], F[33], (float*)d_out);
}

// Round 13
// 807.644 us; speedup vs baseline: 1.0277x; 1.0277x over previous
//
#include <hip/hip_runtime.h>
#include <hip/hip_bf16.h>

#define LNUM 128
#define NNODES 30000
#define NEDGES 150000
#define NSTEPS 5

// NOTE (r17 discovery): d_out is FLOAT32 (reference is pure jnp.float32).
// r12 post-mortem: __syncthreads drains vmcnt(0) -> dbuf + deep prefetch gave
// ZERO cover while LDS 33KB cut occupancy (regression). r13 = T4 done right:
// raw s_barrier + inline-asm counted s_waitcnt vmcnt(1) (steady state) so
// stage k+1 and gather k+2 STAY IN FLIGHT across barriers. Queue accounting:
// per iter issue [stage(2), gather(1)]; wait retires {gather_k, stage_k},
// leaves gather_{k+1}. Arithmetic bit-identical to r11/r12.
// Also: node kernel self-zeroes aggr after last use (drops per-step zero_k).

typedef _Float16 f16;
typedef __attribute__((ext_vector_type(2))) _Float16 f16x2;
typedef __attribute__((ext_vector_type(8))) _Float16 f16x8;
typedef __attribute__((ext_vector_type(4))) float f32x4;

__device__ __forceinline__ void glds16(const void* g, void* l) {
    __builtin_amdgcn_global_load_lds(
        (const __attribute__((address_space(1))) void*)g,
        (__attribute__((address_space(3))) void*)l, 16, 0, 0);
}

__device__ __forceinline__ void atomic_pk_add(f16* addr, f16 lo, f16 hi) {
#if __has_builtin(__builtin_amdgcn_global_atomic_fadd_v2f16)
    f16x2 v; v[0] = lo; v[1] = hi;
    __builtin_amdgcn_global_atomic_fadd_v2f16(
        (__attribute__((address_space(1))) f16x2*)addr, v);
#else
    uint32_t* p = (uint32_t*)addr;
    uint32_t old = *p, assumed;
    do {
        assumed = old;
        union { uint32_t u; f16 h[2]; } c; c.u = assumed;
        c.h[0] += lo; c.h[1] += hi;
        old = atomicCAS(p, assumed, c.u);
    } while (old != assumed);
#endif
}

// ---------------------------------------------------------------------------
// Legacy VALU MLP core: still used by the (small) encode_nodes kernel.
// ---------------------------------------------------------------------------
template<int ROWS, int K, int KP>
__device__ __forceinline__ void mlp_apply(
    const float* __restrict__ xs, float* __restrict__ hv,
    float* __restrict__ mu_s, float* __restrict__ rs_s,
    const float* __restrict__ W1, const float* __restrict__ b1,
    const float* __restrict__ W2, const float* __restrict__ b2,
    const float* __restrict__ g,  const float* __restrict__ be,
    float out[ROWS])
{
    const int t = threadIdx.x;
    float acc[ROWS];
    {
        const float bb = b1[t];
        #pragma unroll
        for (int r = 0; r < ROWS; r++) acc[r] = bb;
    }
    int k = 0;
    for (; k + 4 <= K; k += 4) {
        const float w0 = W1[(k + 0) * LNUM + t];
        const float w1 = W1[(k + 1) * LNUM + t];
        const float w2 = W1[(k + 2) * LNUM + t];
        const float w3 = W1[(k + 3) * LNUM + t];
        #pragma unroll
        for (int r = 0; r < ROWS; r++) {
            const float4 x = *(const float4*)(xs + r * KP + k);
            acc[r] = fmaf(x.x, w0, acc[r]);
            acc[r] = fmaf(x.y, w1, acc[r]);
            acc[r] = fmaf(x.z, w2, acc[r]);
            acc[r] = fmaf(x.w, w3, acc[r]);
        }
    }
    for (; k < K; ++k) {
        const float w = W1[k * LNUM + t];
        #pragma unroll
        for (int r = 0; r < ROWS; r++) acc[r] = fmaf(xs[r * KP + k], w, acc[r]);
    }
    #pragma unroll
    for (int r = 0; r < ROWS; r++) hv[r * LNUM + t] = fmaxf(acc[r], 0.f);
    __syncthreads();
    {
        const float bb = b2[t];
        #pragma unroll
        for (int r = 0; r < ROWS; r++) acc[r] = bb;
    }
    for (int k2 = 0; k2 < LNUM; k2 += 4) {
        const float w0 = W2[(k2 + 0) * LNUM + t];
        const float w1 = W2[(k2 + 1) * LNUM + t];
        const float w2 = W2[(k2 + 2) * LNUM + t];
        const float w3 = W2[(k2 + 3) * LNUM + t];
        #pragma unroll
        for (int r = 0; r < ROWS; r++) {
            const float4 x = *(const float4*)(hv + r * LNUM + k2);
            acc[r] = fmaf(x.x, w0, acc[r]);
            acc[r] = fmaf(x.y, w1, acc[r]);
            acc[r] = fmaf(x.z, w2, acc[r]);
            acc[r] = fmaf(x.w, w3, acc[r]);
        }
    }
    __syncthreads();
    #pragma unroll
    for (int r = 0; r < ROWS; r++) hv[r * LNUM + t] = fmaxf(acc[r], 0.f);
    __syncthreads();
    if (t < ROWS) {
        float s = 0.f, s2 = 0.f;
        for (int kk = 0; kk < LNUM; kk++) {
            const float v = hv[t * LNUM + kk];
            s += v; s2 += v * v;
        }
        const float m = s * (1.0f / LNUM);
        mu_s[t] = m;
        rs_s[t] = rsqrtf(fmaxf(s2 * (1.0f / LNUM) - m * m, 0.f) + 1e-5f);
    }
    __syncthreads();
    const float gg = g[t], bbe = be[t];
    #pragma unroll
    for (int r = 0; r < ROWS; r++)
        out[r] = fmaf(gg * (hv[r * LNUM + t] - mu_s[r]), rs_s[r], bbe);
}

__global__ __launch_bounds__(128) void encode_nodes_k(
    const float* __restrict__ u, const float* __restrict__ load_,
    const float* __restrict__ ntype,
    const float* __restrict__ W1, const float* __restrict__ b1,
    const float* __restrict__ W2, const float* __restrict__ b2,
    const float* __restrict__ g,  const float* __restrict__ be,
    f16* __restrict__ nl)
{
    constexpr int ROWS = 4, K = 12, KP = 12;
    __shared__ __align__(16) float xs[ROWS * KP];
    __shared__ __align__(16) float hv[ROWS * LNUM];
    __shared__ float mu_s[ROWS], rs_s[ROWS];
    const int t = threadIdx.x;
    const int base = blockIdx.x * ROWS;
    if (t < ROWS * K) {
        const int r = t / K, k = t % K;
        const int n = base + r;
        float v;
        if (k < 2)      v = u[n * 2 + k];
        else if (k < 3) v = load_[n];
        else            v = ntype[n * 9 + (k - 3)];
        xs[r * KP + k] = v;
    }
    __syncthreads();
    float out[ROWS];
    mlp_apply<ROWS, K, KP>(xs, hv, mu_s, rs_s, W1, b1, W2, b2, g, be, out);
    #pragma unroll
    for (int r = 0; r < ROWS; r++) nl[(base + r) * LNUM + t] = (f16)out[r];
}

// ---------------------------------------------------------------------------
// Weight prep: f32 [S][K][128] -> f16 hi tables transposed to [S][128][K].
// ---------------------------------------------------------------------------
#define PE1 245760   // 5*384*128 (edge W1)
#define PE2 81920    // 5*128*128 (edge W2)
#define PN1 163840   // 5*256*128 (node W1)
#define PN2 81920    // 5*128*128 (node W2)
#define PQ1 4096     // 128*32    (enc-edge W1, k-padded)
#define PQ2 16384    // 128*128   (enc-edge W2)
#define PTOT (PE1+PE2+PN1+PN2+PQ1+PQ2)

__global__ __launch_bounds__(256) void prep_w_all_k(
    const float* __restrict__ eW1, const float* __restrict__ eW2,
    const float* __restrict__ nW1, const float* __restrict__ nW2,
    const float* __restrict__ qW1, const float* __restrict__ qW2,
    f16* __restrict__ out)
{
    int j = blockIdx.x * 256 + threadIdx.x;
    if (j >= PTOT) return;
    const float* W; int K, kreal; f16* hi; f16* p = out;
    if (j < PE1) { W = eW1; K = 384; kreal = 384; hi = p; }
    else { p += PE1; j -= PE1;
    if (j < PE2) { W = eW2; K = 128; kreal = 128; hi = p; }
    else { p += PE2; j -= PE2;
    if (j < PN1) { W = nW1; K = 256; kreal = 256; hi = p; }
    else { p += PN1; j -= PN1;
    if (j < PN2) { W = nW2; K = 128; kreal = 128; hi = p; }
    else { p += PN2; j -= PN2;
    if (j < PQ1) { W = qW1; K = 32;  kreal = 5;   hi = p; }
    else { p += PQ1; j -= PQ1;
         { W = qW2; K = 128; kreal = 128; hi = p; } } } } } }
    const int k = j % K;
    const int rem = j / K;
    const int n = rem & 127;
    const int s = rem >> 7;
    const float v = (k < kreal) ? W[((size_t)s * kreal + k) * 128 + n] : 0.f;
    hi[j] = (f16)v;
}

// ---------------------------------------------------------------------------
// MFMA MLP, f16 weights/latents/aggr; T4 pipeline (r13).
// 256 thr = 4 waves, 64 rows/block. Dbuf weight LDS (2x8KB). Per chunk:
// counted s_waitcnt vmcnt(1|0) + RAW s_barrier (loads survive the barrier),
// then issue stage(k+1) + gather(k+2), then MFMAs on WH[kc&1].
// Stage cover = 1 full phase; gather cover ~2 phases. Math bit-identical.
// D layout (verified): edge = w*16+lg*4+reg, feature = mf*16+lr.
// MODE: 0 = edge block (Lat=nl16, io=el16 RMW, aggr16 pk-atomics)
//       1 = node block (Lat=aggr16 read + self-zero at end, io=nl16 RMW)
//       2 = edge encoder (Fa=mesh_pos, Fb=u, io=el16 store)
// ---------------------------------------------------------------------------
template<int MODE, int NCH1, int K1S>
__global__ __launch_bounds__(256, 5) void mfma_mlp_k(
    const f16* __restrict__ Lat, const float* __restrict__ Fa,
    const float* __restrict__ Fb,
    f16* __restrict__ io, f16* __restrict__ aggr,
    const int* __restrict__ senders, const int* __restrict__ receivers,
    const f16* __restrict__ W1h, const float* __restrict__ b1,
    const f16* __restrict__ W2h, const float* __restrict__ b2,
    const float* __restrict__ gam, const float* __restrict__ bet,
    int nrows)
{
    __shared__ __align__(16) f16 WH[2][4096];              // dbuf [128][32] swz
    __shared__ __align__(16) unsigned short Yh[64 * 128];  // f16, swizzled, 16KB

    const int t  = threadIdx.x;
    const int w  = t >> 6;
    const int l  = t & 63;
    const int lr = l & 15;
    const int lg = l >> 4;
    const int swz = lg ^ ((lr >> 1) & 3);
    const int base = blockIdx.x * 64;

    const int eg  = base + w * 16 + lr;    // this lane's gather row (A-row)
    const int egc = min(eg, nrows - 1);

    int sv = 0, rv = 0;
    if constexpr (MODE != 1) { sv = senders[egc]; rv = receivers[egc]; }

    float feat[8];
    if constexpr (MODE == 2) {
        const float ax = Fa[sv * 2], ay = Fa[sv * 2 + 1];
        const float bx = Fa[rv * 2], by = Fa[rv * 2 + 1];
        const float rx = ax - bx, ry = ay - by;
        feat[0] = rx; feat[1] = ry; feat[2] = sqrtf(rx * rx + ry * ry);
        feat[3] = Fb[sv * 2] - Fb[rv * 2];
        feat[4] = Fb[sv * 2 + 1] - Fb[rv * 2 + 1];
        feat[5] = 0.f; feat[6] = 0.f; feat[7] = 0.f;
    }

    // r5-verified cooperative stage of one 32-wide K chunk, into buffer buf.
    auto stage = [&](const f16* __restrict__ Wh, const int kst, const int kc,
                     const int buf) {
        #pragma unroll
        for (int i = 0; i < 2; i++) {
            const int c = 2 * w + i;
            const int ophys = c * 1024 + l * 16;
            const int olog  = ophys ^ (((ophys >> 7) & 3) << 4);
            const int row   = olog >> 6;
            const int slot  = (olog >> 4) & 3;
            glds16(Wh + (size_t)row * kst + kc * 32 + slot * 8,
                   (char*)&WH[buf][0] + c * 1024);
        }
    };

    // 3-deep data prefetch registers (f16 chunks; MODE2 uses feat directly).
    uint4 qnA, qnB, qnC;
    auto prefetchTo = [&](int kc, uint4& q) {
        if constexpr (MODE == 0) {
            const f16* src;
            if (kc < 4)      src = Lat + (size_t)sv  * 128 + kc * 32 + lg * 8;
            else if (kc < 8) src = Lat + (size_t)rv  * 128 + (kc - 4) * 32 + lg * 8;
            else             src = io  + (size_t)egc * 128 + (kc - 8) * 32 + lg * 8;
            q = *(const uint4*)src;
        } else if constexpr (MODE == 1) {
            const f16* src;
            if (kc < 4) src = io  + (size_t)egc * 128 + kc * 32 + lg * 8;
            else        src = Lat + (size_t)egc * 128 + (kc - 4) * 32 + lg * 8;
            q = *(const uint4*)src;
        }
    };

    const f32x4 zero4 = {0.f, 0.f, 0.f, 0.f};
    f32x4 acc[8];
    #pragma unroll
    for (int mf = 0; mf < 8; mf++) acc[mf] = zero4;

    if constexpr (MODE != 2) {
        prefetchTo(0, qnA);
        if constexpr (NCH1 > 1) prefetchTo(1, qnB);
    }
    stage(W1h, K1S, 0, 0);

    // ---------------- layer 1: raw barrier + counted vmcnt ---------------
    #pragma unroll
    for (int kc = 0; kc < NCH1; ++kc) {
        // retire {gather_kc, stage_kc}; keep gather_{kc+1} in flight.
        if (MODE != 2 && kc >= 1 && kc + 1 < NCH1)
            asm volatile("s_waitcnt vmcnt(1)" ::: "memory");
        else
            asm volatile("s_waitcnt vmcnt(0)" ::: "memory");
        __builtin_amdgcn_sched_barrier(0);
        __builtin_amdgcn_s_barrier();
        __builtin_amdgcn_sched_barrier(0);
        if (kc + 1 < NCH1) stage(W1h, K1S, kc + 1, (kc + 1) & 1);
        else               stage(W2h, 128,  0,      NCH1 & 1);   // L2 ch0
        if constexpr (MODE != 2) {
            if (kc + 2 < NCH1) {
                if      ((kc + 2) % 3 == 0) prefetchTo(kc + 2, qnA);
                else if ((kc + 2) % 3 == 1) prefetchTo(kc + 2, qnB);
                else                        prefetchTo(kc + 2, qnC);
            }
        }
        f16x8 XHv, XLv;
        bool useXL = false;
        if constexpr (MODE == 2) {
            union { f16 h[8]; f16x8 v; } uh, ul;
            #pragma unroll
            for (int j = 0; j < 8; j++) {
                const float x = (lg == 0) ? feat[j] : 0.f;
                const f16 h = (f16)x;
                uh.h[j] = h;
                ul.h[j] = (f16)(x - (float)h);   // unscaled lo: exact sum
            }
            XHv = uh.v; XLv = ul.v; useXL = true;
        } else {
            union { uint4 q; f16x8 v; } cc;
            cc.q = (kc % 3 == 0) ? qnA : ((kc % 3 == 1) ? qnB : qnC);
            XHv = cc.v;
        }
        #pragma unroll
        for (int mf = 0; mf < 8; mf++) {
            const int off = (mf * 16 + lr) * 64 + (swz << 4);
            const f16x8 wh = *(const f16x8*)((const char*)&WH[kc & 1][0] + off);
            acc[mf] = __builtin_amdgcn_mfma_f32_16x16x32_f16(XHv, wh, acc[mf], 0, 0, 0);
            if (useXL)
                acc[mf] = __builtin_amdgcn_mfma_f32_16x16x32_f16(XLv, wh, acc[mf], 0, 0, 0);
        }
    }

    // layer-1 epilogue: bias+relu -> f16 Y at XOR-swizzled addr (r9-verified;
    // wave-private rows, no barrier needed).
    #pragma unroll
    for (int mf = 0; mf < 8; mf++) {
        const float bb1 = b1[mf * 16 + lr];
        #pragma unroll
        for (int reg = 0; reg < 4; reg++) {
            float v = acc[mf][reg] + bb1;
            v = fmaxf(v, 0.f);
            union { f16 h; unsigned short u; } cc; cc.h = (f16)v;
            const int row = w * 16 + lg * 4 + reg;
            const int cb  = (mf * 16 + lr) * 2;
            *(unsigned short*)((char*)Yh + row * 256 +
                               (cb ^ (((lg * 4 + reg) & 7) << 4))) = cc.u;
        }
        acc[mf] = zero4;
    }

    // ---------------- layer 2 (dbuf continues; 1 MFMA per mf) ------------
    #pragma unroll
    for (int kc = 0; kc < 4; ++kc) {
        asm volatile("s_waitcnt vmcnt(0)" ::: "memory");
        __builtin_amdgcn_sched_barrier(0);
        __builtin_amdgcn_s_barrier();
        __builtin_amdgcn_sched_barrier(0);
        if (kc + 1 < 4) stage(W2h, 128, kc + 1, (NCH1 + kc + 1) & 1);
        union { uint4 q; f16x8 v; } YH;
        {
            const int row = w * 16 + lr;
            const int cb  = (kc * 32 + lg * 8) * 2;
            YH.q = *(const uint4*)((const char*)Yh + row * 256 +
                                   (cb ^ ((lr & 7) << 4)));
        }
        #pragma unroll
        for (int mf = 0; mf < 8; mf++) {
            const int off = (mf * 16 + lr) * 64 + (swz << 4);
            const f16x8 wh = *(const f16x8*)((const char*)&WH[(NCH1 + kc) & 1][0] + off);
            acc[mf] = __builtin_amdgcn_mfma_f32_16x16x32_f16(YH.v, wh, acc[mf], 0, 0, 0);
        }
    }

    // layer-2 epilogue (r5-verified): bias+relu+LN+apply+store (f16 io).
    float vv[8][4];
    float s1[4] = {0, 0, 0, 0}, s2[4] = {0, 0, 0, 0};
    #pragma unroll
    for (int mf = 0; mf < 8; mf++) {
        const float bb2 = b2[mf * 16 + lr];
        #pragma unroll
        for (int reg = 0; reg < 4; reg++) {
            float v = acc[mf][reg] + bb2;
            v = fmaxf(v, 0.f);
            vv[mf][reg] = v;
            s1[reg] += v; s2[reg] += v * v;
        }
    }
    #pragma unroll
    for (int m = 1; m < 16; m <<= 1) {
        #pragma unroll
        for (int reg = 0; reg < 4; reg++) {
            s1[reg] += __shfl_xor(s1[reg], m);
            s2[reg] += __shfl_xor(s2[reg], m);
        }
    }
    float gg[8], b8[8];
    #pragma unroll
    for (int mf = 0; mf < 8; mf++) {
        gg[mf] = gam[mf * 16 + lr];
        b8[mf] = bet[mf * 16 + lr];
    }

    #pragma unroll
    for (int reg = 0; reg < 4; reg++) {
        const float mu = s1[reg] * (1.f / 128.f);
        const float rs = rsqrtf(fmaxf(s2[reg] * (1.f / 128.f) - mu * mu, 0.f) + 1e-5f);
        const int row = w * 16 + lg * 4 + reg;
        const int idx = base + row;
        if (idx < nrows) {
            if constexpr (MODE == 0) {
                const int rc = receivers[idx];   // uniform across lr-group
                #pragma unroll
                for (int mf = 0; mf < 8; mf++) {
                    const int col = mf * 16 + lr;
                    const float o = gg[mf] * (vv[mf][reg] - mu) * rs + b8[mf];
                    // packed f16 atomic: even lane covers cols (c, c+1)
                    const float op = __shfl_xor(o, 1);
                    if ((lr & 1) == 0)
                        atomic_pk_add(aggr + (size_t)rc * 128 + col,
                                      (f16)o, (f16)op);            // segsum
                    f16* p = io + (size_t)idx * 128 + col;         // el res
                    *p = (f16)((float)*p + o);
                }
            } else if constexpr (MODE == 1) {
                #pragma unroll
                for (int mf = 0; mf < 8; mf++) {
                    const int col = mf * 16 + lr;
                    const float o = gg[mf] * (vv[mf][reg] - mu) * rs + b8[mf];
                    f16* p = io + (size_t)idx * 128 + col;         // nl res
                    *p = (f16)((float)*p + o);
                }
            } else {
                #pragma unroll
                for (int mf = 0; mf < 8; mf++) {
                    const int col = mf * 16 + lr;
                    const float o = gg[mf] * (vv[mf][reg] - mu) * rs + b8[mf];
                    io[(size_t)idx * 128 + col] = (f16)o;          // el enc
                }
            }
        }
    }

    if constexpr (MODE == 1) {
        // self-zero aggr for the next step. All reads of these addresses
        // (by this block only) retired before the L2 barriers we passed.
        const uint4 z = {0, 0, 0, 0};
        #pragma unroll
        for (int c = 0; c < 4; c++)
            *(uint4*)(aggr + (size_t)egc * 128 + c * 32 + lg * 8) = z;
    }
}

// Decoder -> FLOAT32 output, layout [TW, N, TD]. Reads f16 nl.
__global__ __launch_bounds__(128) void decode_k(
    const f16* __restrict__ nl,
    const float* __restrict__ W1, const float* __restrict__ b1,
    const float* __restrict__ W2, const float* __restrict__ b2,
    float* __restrict__ out)
{
    constexpr int NPB = 16;
    __shared__ __align__(16) float xs[NPB * LNUM];
    __shared__ float hh[NPB * 8];
    const int t = threadIdx.x;
    const int base = blockIdx.x * NPB;
    for (int r = 0; r < NPB; r++) xs[r * LNUM + t] = (float)nl[(base + r) * LNUM + t];
    __syncthreads();
    {
        const int node = t >> 3, j = t & 7;
        float a = b1[j];
        for (int k = 0; k < LNUM; k++) a = fmaf(xs[node * LNUM + k], W1[k * 8 + j], a);
        hh[node * 8 + j] = a / (1.f + expf(-a));
    }
    __syncthreads();
    for (int idx = t; idx < NPB * 10; idx += 128) {
        const int node = idx / 10, c = idx % 10;
        float a = b2[c];
        #pragma unroll
        for (int j = 0; j < 8; j++) a = fmaf(hh[node * 8 + j], W2[j * 10 + c], a);
        const int tt = c >> 1, d = c & 1;
        out[(size_t)tt * (NNODES * 2) + (size_t)(base + node) * 2 + d] =
            a * (float)(tt + 1);
    }
}

__global__ __launch_bounds__(256) void zero_k(float* __restrict__ p, int n)
{
    const int i = blockIdx.x * 256 + threadIdx.x;
    if (i < n) p[i] = 0.f;
}

// ---------------------------------------------------------------------------
extern "C" void kernel_launch(void* const* d_in, const int* in_sizes, int n_in,
                              void* d_out, int out_size, void* d_ws, size_t ws_size,
                              hipStream_t stream) {
    const float* F[34];
    for (int i = 0; i < 34; i++) F[i] = (const float*)d_in[i];
    const int* senders   = (const int*)d_in[4];
    const int* receivers = (const int*)d_in[5];

    const size_t nN = (size_t)NNODES * LNUM;
    const size_t nE = (size_t)NEDGES * LNUM;
    f16* nl16   = (f16*)d_ws;               // 7.68 MB
    f16* el16   = nl16 + nN;                // 38.4 MB
    f16* aggr16 = el16 + nE;                // 7.68 MB
    f16* wb     = aggr16 + nN;
    f16 *eW1h = wb;
    f16 *eW2h = eW1h + PE1;
    f16 *nW1h = eW2h + PE2;
    f16 *nW2h = nW1h + PN1;
    f16 *qW1h = nW2h + PN2;
    f16 *qW2h = qW1h + PQ1;

    prep_w_all_k<<<(PTOT + 255) / 256, 256, 0, stream>>>(
        F[18], F[20], F[24], F[26], F[12], F[14], wb);

    encode_nodes_k<<<NNODES / 4, 128, 0, stream>>>(
        F[2], F[3], F[1], F[6], F[7], F[8], F[9], F[10], F[11], nl16);

    const int egrid = (NEDGES + 63) / 64;   // 2344 blocks of 256 threads
    const int ngrid = (NNODES + 63) / 64;   // 469

    // edge encoder (MFMA, computed f32 features -> f16 el)
    mfma_mlp_k<2, 1, 32><<<egrid, 256, 0, stream>>>(
        nullptr, F[0], F[2], el16, nullptr, senders, receivers,
        qW1h, F[13], qW2h, F[15], F[16], F[17], NEDGES);

    // aggr zeroed once; thereafter the node kernel self-zeroes it.
    zero_k<<<(NNODES * 64 + 255) / 256, 256, 0, stream>>>(
        (float*)aggr16, NNODES * 64);

    for (int s = 0; s < NSTEPS; s++) {
        mfma_mlp_k<0, 12, 384><<<egrid, 256, 0, stream>>>(
            nl16, nullptr, nullptr, el16, aggr16, senders, receivers,
            eW1h + (size_t)s * 384 * 128, F[19] + s * LNUM,
            eW2h + (size_t)s * 128 * 128, F[21] + s * LNUM,
            F[22] + s * LNUM, F[23] + s * LNUM, NEDGES);
        mfma_mlp_k<1, 8, 256><<<ngrid, 256, 0, stream>>>(
            aggr16, nullptr, nullptr, nl16, aggr16, nullptr, nullptr,
            nW1h + (size_t)s * 256 * 128, F[25] + s * LNUM,
            nW2h + (size_t)s * 128 * 128, F[27] + s * LNUM,
            F[28] + s * LNUM, F[29] + s * LNUM, NNODES);
    }

    decode_k<<<NNODES / 16, 128, 0, stream>>>(
        nl16, F[30], F[31], F[32], F[33], (float*)d_out);
}

// Round 15
// 741.444 us; speedup vs baseline: 1.1195x; 1.0893x over previous
//
#include <hip/hip_runtime.h>
#include <hip/hip_bf16.h>

#define LNUM 128
#define NNODES 30000
#define NEDGES 150000
#define NSTEPS 5

// NOTE (r17 discovery): d_out is FLOAT32 (reference is pure jnp.float32).
// r14 post-mortem: FAILED (absmax 1.28, deterministic). Root cause: vmcnt(N)
// accounting assumed program-order vmem issue, but hipcc reorders independent
// vmem ops (gather hoisted above glds pair) -> vmcnt(1) left half a weight
// stage in flight while MFMAs read that buffer. r15: pin issue order with
// __builtin_amdgcn_sched_barrier(0) between EVERY vmem-issue group
// (gather | stage | gather) in prologue and loop body -> queue at each head
// is exactly [g_k, s_k a, s_k b, g_{k+1}]; vmcnt(1) provably retires the
// stage. Everything else = r14 (LDS union 24.6KB, 6 blk/CU, single-buffered
// L2 with order-independent vmcnt(0)). Arithmetic bit-identical to r11/r13.

typedef _Float16 f16;
typedef __attribute__((ext_vector_type(2))) _Float16 f16x2;
typedef __attribute__((ext_vector_type(8))) _Float16 f16x8;
typedef __attribute__((ext_vector_type(4))) float f32x4;

#define SB() __builtin_amdgcn_sched_barrier(0)

__device__ __forceinline__ void glds16(const void* g, void* l) {
    __builtin_amdgcn_global_load_lds(
        (const __attribute__((address_space(1))) void*)g,
        (__attribute__((address_space(3))) void*)l, 16, 0, 0);
}

__device__ __forceinline__ void atomic_pk_add(f16* addr, f16 lo, f16 hi) {
#if __has_builtin(__builtin_amdgcn_global_atomic_fadd_v2f16)
    f16x2 v; v[0] = lo; v[1] = hi;
    __builtin_amdgcn_global_atomic_fadd_v2f16(
        (__attribute__((address_space(1))) f16x2*)addr, v);
#else
    uint32_t* p = (uint32_t*)addr;
    uint32_t old = *p, assumed;
    do {
        assumed = old;
        union { uint32_t u; f16 h[2]; } c; c.u = assumed;
        c.h[0] += lo; c.h[1] += hi;
        old = atomicCAS(p, assumed, c.u);
    } while (old != assumed);
#endif
}

// ---------------------------------------------------------------------------
// Legacy VALU MLP core: still used by the (small) encode_nodes kernel.
// ---------------------------------------------------------------------------
template<int ROWS, int K, int KP>
__device__ __forceinline__ void mlp_apply(
    const float* __restrict__ xs, float* __restrict__ hv,
    float* __restrict__ mu_s, float* __restrict__ rs_s,
    const float* __restrict__ W1, const float* __restrict__ b1,
    const float* __restrict__ W2, const float* __restrict__ b2,
    const float* __restrict__ g,  const float* __restrict__ be,
    float out[ROWS])
{
    const int t = threadIdx.x;
    float acc[ROWS];
    {
        const float bb = b1[t];
        #pragma unroll
        for (int r = 0; r < ROWS; r++) acc[r] = bb;
    }
    int k = 0;
    for (; k + 4 <= K; k += 4) {
        const float w0 = W1[(k + 0) * LNUM + t];
        const float w1 = W1[(k + 1) * LNUM + t];
        const float w2 = W1[(k + 2) * LNUM + t];
        const float w3 = W1[(k + 3) * LNUM + t];
        #pragma unroll
        for (int r = 0; r < ROWS; r++) {
            const float4 x = *(const float4*)(xs + r * KP + k);
            acc[r] = fmaf(x.x, w0, acc[r]);
            acc[r] = fmaf(x.y, w1, acc[r]);
            acc[r] = fmaf(x.z, w2, acc[r]);
            acc[r] = fmaf(x.w, w3, acc[r]);
        }
    }
    for (; k < K; ++k) {
        const float w = W1[k * LNUM + t];
        #pragma unroll
        for (int r = 0; r < ROWS; r++) acc[r] = fmaf(xs[r * KP + k], w, acc[r]);
    }
    #pragma unroll
    for (int r = 0; r < ROWS; r++) hv[r * LNUM + t] = fmaxf(acc[r], 0.f);
    __syncthreads();
    {
        const float bb = b2[t];
        #pragma unroll
        for (int r = 0; r < ROWS; r++) acc[r] = bb;
    }
    for (int k2 = 0; k2 < LNUM; k2 += 4) {
        const float w0 = W2[(k2 + 0) * LNUM + t];
        const float w1 = W2[(k2 + 1) * LNUM + t];
        const float w2 = W2[(k2 + 2) * LNUM + t];
        const float w3 = W2[(k2 + 3) * LNUM + t];
        #pragma unroll
        for (int r = 0; r < ROWS; r++) {
            const float4 x = *(const float4*)(hv + r * LNUM + k2);
            acc[r] = fmaf(x.x, w0, acc[r]);
            acc[r] = fmaf(x.y, w1, acc[r]);
            acc[r] = fmaf(x.z, w2, acc[r]);
            acc[r] = fmaf(x.w, w3, acc[r]);
        }
    }
    __syncthreads();
    #pragma unroll
    for (int r = 0; r < ROWS; r++) hv[r * LNUM + t] = fmaxf(acc[r], 0.f);
    __syncthreads();
    if (t < ROWS) {
        float s = 0.f, s2 = 0.f;
        for (int kk = 0; kk < LNUM; kk++) {
            const float v = hv[t * LNUM + kk];
            s += v; s2 += v * v;
        }
        const float m = s * (1.0f / LNUM);
        mu_s[t] = m;
        rs_s[t] = rsqrtf(fmaxf(s2 * (1.0f / LNUM) - m * m, 0.f) + 1e-5f);
    }
    __syncthreads();
    const float gg = g[t], bbe = be[t];
    #pragma unroll
    for (int r = 0; r < ROWS; r++)
        out[r] = fmaf(gg * (hv[r * LNUM + t] - mu_s[r]), rs_s[r], bbe);
}

__global__ __launch_bounds__(128) void encode_nodes_k(
    const float* __restrict__ u, const float* __restrict__ load_,
    const float* __restrict__ ntype,
    const float* __restrict__ W1, const float* __restrict__ b1,
    const float* __restrict__ W2, const float* __restrict__ b2,
    const float* __restrict__ g,  const float* __restrict__ be,
    f16* __restrict__ nl)
{
    constexpr int ROWS = 4, K = 12, KP = 12;
    __shared__ __align__(16) float xs[ROWS * KP];
    __shared__ __align__(16) float hv[ROWS * LNUM];
    __shared__ float mu_s[ROWS], rs_s[ROWS];
    const int t = threadIdx.x;
    const int base = blockIdx.x * ROWS;
    if (t < ROWS * K) {
        const int r = t / K, k = t % K;
        const int n = base + r;
        float v;
        if (k < 2)      v = u[n * 2 + k];
        else if (k < 3) v = load_[n];
        else            v = ntype[n * 9 + (k - 3)];
        xs[r * KP + k] = v;
    }
    __syncthreads();
    float out[ROWS];
    mlp_apply<ROWS, K, KP>(xs, hv, mu_s, rs_s, W1, b1, W2, b2, g, be, out);
    #pragma unroll
    for (int r = 0; r < ROWS; r++) nl[(base + r) * LNUM + t] = (f16)out[r];
}

// ---------------------------------------------------------------------------
// Weight prep: f32 [S][K][128] -> f16 hi tables transposed to [S][128][K].
// ---------------------------------------------------------------------------
#define PE1 245760   // 5*384*128 (edge W1)
#define PE2 81920    // 5*128*128 (edge W2)
#define PN1 163840   // 5*256*128 (node W1)
#define PN2 81920    // 5*128*128 (node W2)
#define PQ1 4096     // 128*32    (enc-edge W1, k-padded)
#define PQ2 16384    // 128*128   (enc-edge W2)
#define PTOT (PE1+PE2+PN1+PN2+PQ1+PQ2)

__global__ __launch_bounds__(256) void prep_w_all_k(
    const float* __restrict__ eW1, const float* __restrict__ eW2,
    const float* __restrict__ nW1, const float* __restrict__ nW2,
    const float* __restrict__ qW1, const float* __restrict__ qW2,
    f16* __restrict__ out)
{
    int j = blockIdx.x * 256 + threadIdx.x;
    if (j >= PTOT) return;
    const float* W; int K, kreal; f16* hi; f16* p = out;
    if (j < PE1) { W = eW1; K = 384; kreal = 384; hi = p; }
    else { p += PE1; j -= PE1;
    if (j < PE2) { W = eW2; K = 128; kreal = 128; hi = p; }
    else { p += PE2; j -= PE2;
    if (j < PN1) { W = nW1; K = 256; kreal = 256; hi = p; }
    else { p += PN1; j -= PN1;
    if (j < PN2) { W = nW2; K = 128; kreal = 128; hi = p; }
    else { p += PN2; j -= PN2;
    if (j < PQ1) { W = qW1; K = 32;  kreal = 5;   hi = p; }
    else { p += PQ1; j -= PQ1;
         { W = qW2; K = 128; kreal = 128; hi = p; } } } } } }
    const int k = j % K;
    const int rem = j / K;
    const int n = rem & 127;
    const int s = rem >> 7;
    const float v = (k < kreal) ? W[((size_t)s * kreal + k) * 128 + n] : 0.f;
    hi[j] = (f16)v;
}

// ---------------------------------------------------------------------------
// MFMA MLP, f16 weights/latents/aggr; T4 pipeline + LDS union (r15).
// SMEM 24KB: L1 dbuf WH0/WH1 = [0,8K)/[8K,16K), counted vmcnt(1) + raw
// barrier per chunk, vmem issue order PINNED via sched_barrier(0) so the
// queue at each head is exactly [g_k, s_k a, s_k b, g_{k+1}].
// L2: Yh = [8K,24K) (wave-private rows), W2 single-buffered in [0,8K) with
// order-independent vmcnt(0) waits. Arithmetic bit-identical to r11/r13.
// D layout (verified): edge = w*16+lg*4+reg, feature = mf*16+lr.
// MODE: 0 = edge block (Lat=nl16, io=el16 RMW, aggr16 pk-atomics)
//       1 = node block (Lat=aggr16 read + self-zero at end, io=nl16 RMW)
//       2 = edge encoder (Fa=mesh_pos, Fb=u, io=el16 store)
// ---------------------------------------------------------------------------
template<int MODE, int NCH1, int K1S>
__global__ __launch_bounds__(256, 6) void mfma_mlp_k(
    const f16* __restrict__ Lat, const float* __restrict__ Fa,
    const float* __restrict__ Fb,
    f16* __restrict__ io, f16* __restrict__ aggr,
    const int* __restrict__ senders, const int* __restrict__ receivers,
    const f16* __restrict__ W1h, const float* __restrict__ b1,
    const f16* __restrict__ W2h, const float* __restrict__ b2,
    const float* __restrict__ gam, const float* __restrict__ bet,
    int nrows)
{
    __shared__ __align__(16) char SMEM[24576];   // L1: WH0|WH1 ; L2: WH0|Yh

    const int t  = threadIdx.x;
    const int w  = t >> 6;
    const int l  = t & 63;
    const int lr = l & 15;
    const int lg = l >> 4;
    const int swz = lg ^ ((lr >> 1) & 3);
    const int base = blockIdx.x * 64;

    const int eg  = base + w * 16 + lr;    // this lane's gather row (A-row)
    const int egc = min(eg, nrows - 1);

    int sv = 0, rv = 0;
    if constexpr (MODE != 1) { sv = senders[egc]; rv = receivers[egc]; }

    float feat[8];
    if constexpr (MODE == 2) {
        const float ax = Fa[sv * 2], ay = Fa[sv * 2 + 1];
        const float bx = Fa[rv * 2], by = Fa[rv * 2 + 1];
        const float rx = ax - bx, ry = ay - by;
        feat[0] = rx; feat[1] = ry; feat[2] = sqrtf(rx * rx + ry * ry);
        feat[3] = Fb[sv * 2] - Fb[rv * 2];
        feat[4] = Fb[sv * 2 + 1] - Fb[rv * 2 + 1];
        feat[5] = 0.f; feat[6] = 0.f; feat[7] = 0.f;
    }

    // r5-verified cooperative stage of one 32-wide K chunk into SMEM+buf*8K.
    auto stage = [&](const f16* __restrict__ Wh, const int kst, const int kc,
                     const int buf) {
        #pragma unroll
        for (int i = 0; i < 2; i++) {
            const int c = 2 * w + i;
            const int ophys = c * 1024 + l * 16;
            const int olog  = ophys ^ (((ophys >> 7) & 3) << 4);
            const int row   = olog >> 6;
            const int slot  = (olog >> 4) & 3;
            glds16(Wh + (size_t)row * kst + kc * 32 + slot * 8,
                   SMEM + buf * 8192 + c * 1024);
        }
    };

    // 3-reg rotating data prefetch (f16 chunks; MODE2 uses feat directly).
    uint4 qnA, qnB, qnC;
    auto prefetchTo = [&](int kc, uint4& q) {
        if constexpr (MODE == 0) {
            const f16* src;
            if (kc < 4)      src = Lat + (size_t)sv  * 128 + kc * 32 + lg * 8;
            else if (kc < 8) src = Lat + (size_t)rv  * 128 + (kc - 4) * 32 + lg * 8;
            else             src = io  + (size_t)egc * 128 + (kc - 8) * 32 + lg * 8;
            q = *(const uint4*)src;
        } else if constexpr (MODE == 1) {
            const f16* src;
            if (kc < 4) src = io  + (size_t)egc * 128 + kc * 32 + lg * 8;
            else        src = Lat + (size_t)egc * 128 + (kc - 4) * 32 + lg * 8;
            q = *(const uint4*)src;
        }
    };

    const f32x4 zero4 = {0.f, 0.f, 0.f, 0.f};
    f32x4 acc[8];
    #pragma unroll
    for (int mf = 0; mf < 8; mf++) acc[mf] = zero4;

    // prologue, issue order PINNED: [g0] [s0a s0b] [g1]
    if constexpr (MODE != 2) { prefetchTo(0, qnA); }
    SB();
    stage(W1h, K1S, 0, 0);
    SB();
    if constexpr (MODE != 2) { if constexpr (NCH1 > 1) prefetchTo(1, qnB); }
    SB();

    // ---------------- layer 1: dbuf + raw barrier + counted vmcnt --------
    #pragma unroll
    for (int kc = 0; kc < NCH1; ++kc) {
        // queue here is exactly [g_kc, s_kc a, s_kc b, g_{kc+1}]:
        // vmcnt(1) retires g_kc + both stage ops, keeps g_{kc+1} in flight.
        if (MODE != 2 && kc + 1 < NCH1)
            asm volatile("s_waitcnt vmcnt(1)" ::: "memory");
        else
            asm volatile("s_waitcnt vmcnt(0)" ::: "memory");
        SB();
        __builtin_amdgcn_s_barrier();
        SB();
        if (kc + 1 < NCH1) stage(W1h, K1S, kc + 1, (kc + 1) & 1);
        SB();                                   // pin: stage before gather
        if constexpr (MODE != 2) {
            if (kc + 2 < NCH1) {
                if      ((kc + 2) % 3 == 0) prefetchTo(kc + 2, qnA);
                else if ((kc + 2) % 3 == 1) prefetchTo(kc + 2, qnB);
                else                        prefetchTo(kc + 2, qnC);
            }
        }
        SB();                                   // pin: gather before compute
        f16x8 XHv, XLv;
        bool useXL = false;
        if constexpr (MODE == 2) {
            union { f16 h[8]; f16x8 v; } uh, ul;
            #pragma unroll
            for (int j = 0; j < 8; j++) {
                const float x = (lg == 0) ? feat[j] : 0.f;
                const f16 h = (f16)x;
                uh.h[j] = h;
                ul.h[j] = (f16)(x - (float)h);   // unscaled lo: exact sum
            }
            XHv = uh.v; XLv = ul.v; useXL = true;
        } else {
            union { uint4 q; f16x8 v; } cc;
            cc.q = (kc % 3 == 0) ? qnA : ((kc % 3 == 1) ? qnB : qnC);
            XHv = cc.v;
        }
        #pragma unroll
        for (int mf = 0; mf < 8; mf++) {
            const int off = (mf * 16 + lr) * 64 + (swz << 4);
            const f16x8 wh = *(const f16x8*)(SMEM + (kc & 1) * 8192 + off);
            acc[mf] = __builtin_amdgcn_mfma_f32_16x16x32_f16(XHv, wh, acc[mf], 0, 0, 0);
            if (useXL)
                acc[mf] = __builtin_amdgcn_mfma_f32_16x16x32_f16(XLv, wh, acc[mf], 0, 0, 0);
        }
    }

    // -------- layer boundary: all WH reads done BEFORE Yh writes ---------
    asm volatile("s_waitcnt lgkmcnt(0)" ::: "memory");
    SB();
    __builtin_amdgcn_s_barrier();
    SB();
    stage(W2h, 128, 0, 0);   // W2 ch0 -> WH0; covered by Yh epilogue below
    SB();

    // layer-1 epilogue: bias+relu -> f16 Y at XOR-swizzled addr
    // (Yh = SMEM+8192, wave-private rows).
    #pragma unroll
    for (int mf = 0; mf < 8; mf++) {
        const float bb1 = b1[mf * 16 + lr];
        #pragma unroll
        for (int reg = 0; reg < 4; reg++) {
            float v = acc[mf][reg] + bb1;
            v = fmaxf(v, 0.f);
            union { f16 h; unsigned short u; } cc; cc.h = (f16)v;
            const int row = w * 16 + lg * 4 + reg;
            const int cb  = (mf * 16 + lr) * 2;
            *(unsigned short*)(SMEM + 8192 + row * 256 +
                               (cb ^ (((lg * 4 + reg) & 7) << 4))) = cc.u;
        }
        acc[mf] = zero4;
    }

    // ---------------- layer 2: single-buffer W2 in WH0, Yh in [8K,24K) ---
    #pragma unroll
    for (int kc = 0; kc < 4; ++kc) {
        asm volatile("s_waitcnt vmcnt(0)" ::: "memory");   // stage(kc) landed
        SB();
        __builtin_amdgcn_s_barrier();
        SB();
        union { uint4 q; f16x8 v; } YH;
        {
            const int row = w * 16 + lr;
            const int cb  = (kc * 32 + lg * 8) * 2;
            YH.q = *(const uint4*)(SMEM + 8192 + row * 256 +
                                   (cb ^ ((lr & 7) << 4)));
        }
        #pragma unroll
        for (int mf = 0; mf < 8; mf++) {
            const int off = (mf * 16 + lr) * 64 + (swz << 4);
            const f16x8 wh = *(const f16x8*)(SMEM + off);
            acc[mf] = __builtin_amdgcn_mfma_f32_16x16x32_f16(YH.v, wh, acc[mf], 0, 0, 0);
        }
        if (kc + 1 < 4) {
            // WAR: all waves done reading WH0 chunk kc before restaging
            asm volatile("s_waitcnt lgkmcnt(0)" ::: "memory");
            SB();
            __builtin_amdgcn_s_barrier();
            SB();
            stage(W2h, 128, kc + 1, 0);
            SB();
        }
    }

    // layer-2 epilogue (r5-verified): bias+relu+LN+apply+store (f16 io).
    float vv[8][4];
    float s1[4] = {0, 0, 0, 0}, s2[4] = {0, 0, 0, 0};
    #pragma unroll
    for (int mf = 0; mf < 8; mf++) {
        const float bb2 = b2[mf * 16 + lr];
        #pragma unroll
        for (int reg = 0; reg < 4; reg++) {
            float v = acc[mf][reg] + bb2;
            v = fmaxf(v, 0.f);
            vv[mf][reg] = v;
            s1[reg] += v; s2[reg] += v * v;
        }
    }
    #pragma unroll
    for (int m = 1; m < 16; m <<= 1) {
        #pragma unroll
        for (int reg = 0; reg < 4; reg++) {
            s1[reg] += __shfl_xor(s1[reg], m);
            s2[reg] += __shfl_xor(s2[reg], m);
        }
    }
    float gg[8], b8[8];
    #pragma unroll
    for (int mf = 0; mf < 8; mf++) {
        gg[mf] = gam[mf * 16 + lr];
        b8[mf] = bet[mf * 16 + lr];
    }

    #pragma unroll
    for (int reg = 0; reg < 4; reg++) {
        const float mu = s1[reg] * (1.f / 128.f);
        const float rs = rsqrtf(fmaxf(s2[reg] * (1.f / 128.f) - mu * mu, 0.f) + 1e-5f);
        const int row = w * 16 + lg * 4 + reg;
        const int idx = base + row;
        if (idx < nrows) {
            if constexpr (MODE == 0) {
                const int rc = receivers[idx];   // uniform across lr-group
                #pragma unroll
                for (int mf = 0; mf < 8; mf++) {
                    const int col = mf * 16 + lr;
                    const float o = gg[mf] * (vv[mf][reg] - mu) * rs + b8[mf];
                    // packed f16 atomic: even lane covers cols (c, c+1)
                    const float op = __shfl_xor(o, 1);
                    if ((lr & 1) == 0)
                        atomic_pk_add(aggr + (size_t)rc * 128 + col,
                                      (f16)o, (f16)op);            // segsum
                    f16* p = io + (size_t)idx * 128 + col;         // el res
                    *p = (f16)((float)*p + o);
                }
            } else if constexpr (MODE == 1) {
                #pragma unroll
                for (int mf = 0; mf < 8; mf++) {
                    const int col = mf * 16 + lr;
                    const float o = gg[mf] * (vv[mf][reg] - mu) * rs + b8[mf];
                    f16* p = io + (size_t)idx * 128 + col;         // nl res
                    *p = (f16)((float)*p + o);
                }
            } else {
                #pragma unroll
                for (int mf = 0; mf < 8; mf++) {
                    const int col = mf * 16 + lr;
                    const float o = gg[mf] * (vv[mf][reg] - mu) * rs + b8[mf];
                    io[(size_t)idx * 128 + col] = (f16)o;          // el enc
                }
            }
        }
    }

    if constexpr (MODE == 1) {
        // self-zero aggr for the next step (this block's own rows only).
        const uint4 z = {0, 0, 0, 0};
        #pragma unroll
        for (int c = 0; c < 4; c++)
            *(uint4*)(aggr + (size_t)egc * 128 + c * 32 + lg * 8) = z;
    }
}

// Decoder -> FLOAT32 output, layout [TW, N, TD]. Reads f16 nl.
__global__ __launch_bounds__(128) void decode_k(
    const f16* __restrict__ nl,
    const float* __restrict__ W1, const float* __restrict__ b1,
    const float* __restrict__ W2, const float* __restrict__ b2,
    float* __restrict__ out)
{
    constexpr int NPB = 16;
    __shared__ __align__(16) float xs[NPB * LNUM];
    __shared__ float hh[NPB * 8];
    const int t = threadIdx.x;
    const int base = blockIdx.x * NPB;
    for (int r = 0; r < NPB; r++) xs[r * LNUM + t] = (float)nl[(base + r) * LNUM + t];
    __syncthreads();
    {
        const int node = t >> 3, j = t & 7;
        float a = b1[j];
        for (int k = 0; k < LNUM; k++) a = fmaf(xs[node * LNUM + k], W1[k * 8 + j], a);
        hh[node * 8 + j] = a / (1.f + expf(-a));
    }
    __syncthreads();
    for (int idx = t; idx < NPB * 10; idx += 128) {
        const int node = idx / 10, c = idx % 10;
        float a = b2[c];
        #pragma unroll
        for (int j = 0; j < 8; j++) a = fmaf(hh[node * 8 + j], W2[j * 10 + c], a);
        const int tt = c >> 1, d = c & 1;
        out[(size_t)tt * (NNODES * 2) + (size_t)(base + node) * 2 + d] =
            a * (float)(tt + 1);
    }
}

__global__ __launch_bounds__(256) void zero_k(float* __restrict__ p, int n)
{
    const int i = blockIdx.x * 256 + threadIdx.x;
    if (i < n) p[i] = 0.f;
}

// ---------------------------------------------------------------------------
extern "C" void kernel_launch(void* const* d_in, const int* in_sizes, int n_in,
                              void* d_out, int out_size, void* d_ws, size_t ws_size,
                              hipStream_t stream) {
    const float* F[34];
    for (int i = 0; i < 34; i++) F[i] = (const float*)d_in[i];
    const int* senders   = (const int*)d_in[4];
    const int* receivers = (const int*)d_in[5];

    const size_t nN = (size_t)NNODES * LNUM;
    const size_t nE = (size_t)NEDGES * LNUM;
    f16* nl16   = (f16*)d_ws;               // 7.68 MB
    f16* el16   = nl16 + nN;                // 38.4 MB
    f16* aggr16 = el16 + nE;                // 7.68 MB
    f16* wb     = aggr16 + nN;
    f16 *eW1h = wb;
    f16 *eW2h = eW1h + PE1;
    f16 *nW1h = eW2h + PE2;
    f16 *nW2h = nW1h + PN1;
    f16 *qW1h = nW2h + PN2;
    f16 *qW2h = qW1h + PQ1;

    prep_w_all_k<<<(PTOT + 255) / 256, 256, 0, stream>>>(
        F[18], F[20], F[24], F[26], F[12], F[14], wb);

    encode_nodes_k<<<NNODES / 4, 128, 0, stream>>>(
        F[2], F[3], F[1], F[6], F[7], F[8], F[9], F[10], F[11], nl16);

    const int egrid = (NEDGES + 63) / 64;   // 2344 blocks of 256 threads
    const int ngrid = (NNODES + 63) / 64;   // 469

    // edge encoder (MFMA, computed f32 features -> f16 el)
    mfma_mlp_k<2, 1, 32><<<egrid, 256, 0, stream>>>(
        nullptr, F[0], F[2], el16, nullptr, senders, receivers,
        qW1h, F[13], qW2h, F[15], F[16], F[17], NEDGES);

    // aggr zeroed once; thereafter the node kernel self-zeroes it.
    zero_k<<<(NNODES * 64 + 255) / 256, 256, 0, stream>>>(
        (float*)aggr16, NNODES * 64);

    for (int s = 0; s < NSTEPS; s++) {
        mfma_mlp_k<0, 12, 384><<<egrid, 256, 0, stream>>>(
            nl16, nullptr, nullptr, el16, aggr16, senders, receivers,
            eW1h + (size_t)s * 384 * 128, F[19] + s * LNUM,
            eW2h + (size_t)s * 128 * 128, F[21] + s * LNUM,
            F[22] + s * LNUM, F[23] + s * LNUM, NEDGES);
        mfma_mlp_k<1, 8, 256><<<ngrid, 256, 0, stream>>>(
            aggr16, nullptr, nullptr, nl16, aggr16, nullptr, nullptr,
            nW1h + (size_t)s * 256 * 128, F[25] + s * LNUM,
            nW2h + (size_t)s * 128 * 128, F[27] + s * LNUM,
            F[28] + s * LNUM, F[29] + s * LNUM, NNODES);
    }

    decode_k<<<NNODES / 16, 128, 0, stream>>>(
        nl16, F[30], F[31], F[32], F[33], (float*)d_out);
}